// Round 6
// baseline (1098.684 us; speedup 1.0000x reference)
//
#include <hip/hip_runtime.h>
#include <hip/hip_bf16.h>

typedef __attribute__((ext_vector_type(8))) short bf16x8;
typedef __attribute__((ext_vector_type(4))) float f32x4;

#define C_    1024
#define MROWS 32768   // B*T*QH
#define D_    256     // per-head dim
#define S_TOT 4096
#define SCH   64      // S-chunk (two 32-groups)
#define NCH   (S_TOT / SCH)   // 64 chunks
#define CHW   16384   // shorts per 64-chunk K or V tile (64*256)

__device__ __forceinline__ unsigned short f2bf(float f) {
  union { float f; unsigned int u; } v; v.f = f;
  unsigned int u = v.u;
  u += 0x7fffu + ((u >> 16) & 1u);   // round-to-nearest-even
  return (unsigned short)(u >> 16);
}

__device__ __forceinline__ void async16(const void* g, void* l) {
  __builtin_amdgcn_global_load_lds(
      (const __attribute__((address_space(1))) unsigned int*)g,
      (__attribute__((address_space(3))) unsigned int*)l, 16, 0, 0);
}

// ---------------- LayerNorm -> bf16 (one wave per row) ----------------
__global__ __launch_bounds__(256) void ln_kernel(const float* __restrict__ res,
                                                 const float* __restrict__ g,
                                                 const float* __restrict__ b,
                                                 unsigned short* __restrict__ xq) {
  int wave = threadIdx.x >> 6, lane = threadIdx.x & 63;
  int row = blockIdx.x * 4 + wave;
  const float* r = res + (size_t)row * C_;
  float4 x[4];
  float s = 0.f, s2 = 0.f;
  #pragma unroll
  for (int i = 0; i < 4; ++i) {
    x[i] = *(const float4*)(r + i * 256 + lane * 4);
    s  += x[i].x + x[i].y + x[i].z + x[i].w;
    s2 += x[i].x * x[i].x + x[i].y * x[i].y + x[i].z * x[i].z + x[i].w * x[i].w;
  }
  #pragma unroll
  for (int off = 32; off > 0; off >>= 1) {
    s  += __shfl_xor(s, off, 64);
    s2 += __shfl_xor(s2, off, 64);
  }
  float mu  = s * (1.0f / C_);
  float var = s2 * (1.0f / C_) - mu * mu;
  float rs  = rsqrtf(var + 1e-5f);
  #pragma unroll
  for (int i = 0; i < 4; ++i) {
    int c = i * 256 + lane * 4;
    float4 gg = *(const float4*)(g + c);
    float4 bb = *(const float4*)(b + c);
    unsigned short o[4];
    o[0] = f2bf((x[i].x - mu) * rs * gg.x + bb.x);
    o[1] = f2bf((x[i].y - mu) * rs * gg.y + bb.y);
    o[2] = f2bf((x[i].z - mu) * rs * gg.z + bb.z);
    o[3] = f2bf((x[i].w - mu) * rs * gg.w + bb.w);
    *(ushort4*)(xq + (size_t)row * C_ + c) = *(ushort4*)o;
  }
}

// ---------------- K -> bf16, pre-swizzled into MFMA B-fragment order --------
// kq[((sc2*8+kc)*2+sn)*64+lane][j] = K[s][d],
//   s = sc2*32 + sn*16 + (lane&15), d = kc*32 + (lane>>4)*8 + j
__global__ __launch_bounds__(256) void prep_k(const float* __restrict__ wfc,
                                              unsigned short* __restrict__ kq) {
  int t = blockIdx.x * 256 + threadIdx.x;
  int lane = t & 63;
  int sn  = (t >> 6) & 1;
  int kc  = (t >> 7) & 7;
  int sc2 = t >> 10;
  int s = sc2 * 32 + sn * 16 + (lane & 15);
  int d = kc * 32 + (lane >> 4) * 8;
  const float* src = wfc + (size_t)s * D_ + d;
  float4 a = *(const float4*)src;
  float4 b = *(const float4*)(src + 4);
  unsigned short o[8] = { f2bf(a.x), f2bf(a.y), f2bf(a.z), f2bf(a.w),
                          f2bf(b.x), f2bf(b.y), f2bf(b.z), f2bf(b.w) };
  *(uint4*)(kq + (size_t)t * 8) = *(uint4*)o;
}

// ---------------- V -> bf16, pre-swizzled into MFMA B-fragment order --------
// vq[((sc2*16+dn)*64+lane)*8+j] = V[s][d],
//   s = sc2*32 + (lane>>4)*8 + j, d = dn*16 + (lane&15)
//   V[s][d] = w_proj[(s&3)*256 + d][s>>2]
__global__ __launch_bounds__(256) void prep_v(const float* __restrict__ wproj,
                                              unsigned short* __restrict__ vq) {
  __shared__ unsigned short tile[8192];   // [p=(s&3)*256+d][c=(s_local>>2)] : 1024 x 8
  int b = blockIdx.x;
  int tid = threadIdx.x;
  int c0 = b * 8;
  #pragma unroll
  for (int it = 0; it < 4; ++it) {
    int row = it * 256 + tid;
    const float* src = wproj + (size_t)row * C_ + c0;
    float4 a = *(const float4*)src;
    float4 bb = *(const float4*)(src + 4);
    unsigned short* dst = &tile[row * 8];
    dst[0] = f2bf(a.x);  dst[1] = f2bf(a.y);  dst[2] = f2bf(a.z);  dst[3] = f2bf(a.w);
    dst[4] = f2bf(bb.x); dst[5] = f2bf(bb.y); dst[6] = f2bf(bb.z); dst[7] = f2bf(bb.w);
  }
  __syncthreads();
  #pragma unroll
  for (int it = 0; it < 4; ++it) {
    int slot = it * 256 + tid;
    int lane = slot & 63;
    int dn   = slot >> 6;
    int d = dn * 16 + (lane & 15);
    int sl0 = (lane >> 4) * 8;
    unsigned short o[8];
    #pragma unroll
    for (int j = 0; j < 8; ++j) {
      int sl = sl0 + j;
      o[j] = tile[((sl & 3) * 256 + d) * 8 + (sl >> 2)];
    }
    *(uint4*)(vq + (size_t)b * 8192 + (size_t)slot * 8) = *(uint4*)o;
  }
}

// ---------------- fused main: wave-specialized producer/consumer ------------
// Waves 0-3 (producers): scores(sc) -> P[sc&1].  64 rows x 32 s each (2M x 2S).
// Waves 4-7 (consumers): PV(sc-1) from P/V[prv]. 64 rows x 128 d each (2M x 2N).
// One barrier per 64-chunk.  LDS: K 2x32K + V 2x32K + P 2x16K = 160 KiB exactly.
// P is XOR-swizzled (short idx ^= (row&7)<<3), write/read use the same involution.
// REGISTER BUDGET: persistent acc(128)+qf(64)=192 VGPRs in every wave (static
// allocation across the role branch).  hipcc's default heuristic targets
// 4 waves/EU = 128 VGPRs and spills acc to scratch (R4/R5: FETCH 9.4x, 790us).
// amdgpu_waves_per_eu(2,2) pins the real occupancy (1 block/CU from LDS =
// 2 waves/EU) so the allocator gets the full 256-VGPR budget.
__global__ __launch_bounds__(512)
__attribute__((amdgpu_waves_per_eu(2, 2)))
void mlpmha_main(
    const unsigned short* __restrict__ xq,
    const unsigned short* __restrict__ kq,
    const unsigned short* __restrict__ vq,
    const float* __restrict__ res,
    float* __restrict__ out) {
  __shared__ unsigned short ldsK[2][CHW];    // 2 x 32 KB
  __shared__ unsigned short ldsV[2][CHW];    // 2 x 32 KB
  __shared__ unsigned short ldsP[2][8192];   // 2 x 16 KB : [row 128][col 64] swizzled

  int tid  = threadIdx.x;
  int wave = tid >> 6;
  int lane = tid & 63;
  int l16  = lane & 15;
  int quad = lane >> 4;
  int wgM  = blockIdx.x * 128;

  int soff = tid * 8;   // DMA staging offset (shorts): uniform base + lane*16B

  auto issue32 = [&](const unsigned short* gbase, unsigned short* lbase) {
    #pragma unroll
    for (int seg = 0; seg < 4; ++seg)
      async16(gbase + soff + seg * 4096, lbase + soff + seg * 4096);
  };

  // ---- producer state (waves 0-3): 64 rows x 32 s
  int miP = (wave >> 1) & 1;   // 64-row group
  int sg  = wave & 1;          // 32-s group
  bf16x8 qf[4][8];
  if (wave < 4) {
    #pragma unroll
    for (int mt = 0; mt < 4; ++mt) {
      const unsigned short* qr =
          xq + (size_t)(wgM + miP * 64 + mt * 16 + l16) * D_ + quad * 8;
      #pragma unroll
      for (int kc = 0; kc < 8; ++kc) qf[mt][kc] = *(const bf16x8*)(qr + kc * 32);
    }
  }

  // ---- consumer state (waves 4-7): 64 rows x 128 d
  int cw  = wave - 4;
  int mi2 = (cw >> 1) & 1;
  int ni  = cw & 1;
  f32x4 acc[4][8];   // [mt2][dnl]
  #pragma unroll
  for (int i = 0; i < 4; ++i)
    #pragma unroll
    for (int j = 0; j < 8; ++j) acc[i][j] = (f32x4){0.f, 0.f, 0.f, 0.f};

  auto scores_do = [&](const unsigned short* kbuf, unsigned short* pbuf) {
    const unsigned short* kb_base = kbuf + sg * 8192 + lane * 8;
    // st outer: halves the live sacc transient (16 VGPRs instead of 32)
    #pragma unroll
    for (int st = 0; st < 2; ++st) {
      f32x4 sacc[4];
      #pragma unroll
      for (int mt = 0; mt < 4; ++mt) sacc[mt] = (f32x4){0.f, 0.f, 0.f, 0.f};
      #pragma unroll
      for (int kc = 0; kc < 8; ++kc) {
        bf16x8 kb = *(const bf16x8*)(kb_base + (kc * 2 + st) * 512);
        #pragma unroll
        for (int mt = 0; mt < 4; ++mt)
          sacc[mt] = __builtin_amdgcn_mfma_f32_16x16x32_bf16(qf[mt][kc], kb, sacc[mt], 0, 0, 0);
      }
      #pragma unroll
      for (int mt = 0; mt < 4; ++mt)
        #pragma unroll
        for (int r = 0; r < 4; ++r) {
          float v = sacc[mt][r];
          v = v > 0.f ? v * v : 0.f;
          int row = miP * 64 + mt * 16 + quad * 4 + r;
          int col = sg * 32 + st * 16 + l16;
          pbuf[(row * 64 + col) ^ ((row & 7) << 3)] = f2bf(v);
        }
    }
  };

  auto pv_do = [&](const unsigned short* pbuf, const unsigned short* vbuf) {
    #pragma unroll
    for (int ks = 0; ks < 2; ++ks) {
      bf16x8 pa[4];
      #pragma unroll
      for (int mt2 = 0; mt2 < 4; ++mt2) {
        int row = mi2 * 64 + mt2 * 16 + l16;
        pa[mt2] = *(const bf16x8*)(pbuf + ((row * 64 + ks * 32 + quad * 8) ^ ((row & 7) << 3)));
      }
      bf16x8 vb[8];
      #pragma unroll
      for (int dnl = 0; dnl < 8; ++dnl)
        vb[dnl] = *(const bf16x8*)(vbuf + ks * 8192 + ((ni * 8 + dnl) * 64 + lane) * 8);
      #pragma unroll
      for (int mt2 = 0; mt2 < 4; ++mt2)
        #pragma unroll
        for (int dnl = 0; dnl < 8; ++dnl)
          acc[mt2][dnl] = __builtin_amdgcn_mfma_f32_16x16x32_bf16(pa[mt2], vb[dnl], acc[mt2][dnl], 0, 0, 0);
    }
  };

  // ---- prologue: K(0)
  issue32(kq, ldsK[0]);
  __syncthreads();

  // ---- body 0: stage K(1), V(0); producers compute P(0)
  issue32(kq + CHW, ldsK[1]);
  issue32(vq, ldsV[0]);
  if (wave < 4) scores_do(ldsK[0], ldsP[0]);
  __syncthreads();

  // ---- main loop
  for (int sc = 1; sc < NCH; ++sc) {
    int cur = sc & 1;
    int prv = 1 - cur;
    if (sc + 1 < NCH) issue32(kq + (size_t)(sc + 1) * CHW, ldsK[1 - cur]);
    issue32(vq + (size_t)sc * CHW, ldsV[cur]);
    if (wave < 4) {
      scores_do(ldsK[cur], ldsP[cur]);
    } else {
      pv_do(ldsP[prv], ldsV[prv]);
    }
    __syncthreads();
  }

  // ---- tail: PV(NCH-1) from buffers [1]
  if (wave >= 4) pv_do(ldsP[1], ldsV[1]);

  // ---- epilogue: out = residual + acc (consumer waves only)
  if (wave >= 4) {
    #pragma unroll
    for (int mt2 = 0; mt2 < 4; ++mt2)
      #pragma unroll
      for (int r = 0; r < 4; ++r) {
        size_t row = (size_t)(wgM + mi2 * 64 + mt2 * 16 + quad * 4 + r) * D_;
        #pragma unroll
        for (int dnl = 0; dnl < 8; ++dnl) {
          size_t idx = row + ni * 128 + dnl * 16 + l16;
          out[idx] = res[idx] + acc[mt2][dnl][r];
        }
      }
  }
}

extern "C" void kernel_launch(void* const* d_in, const int* in_sizes, int n_in,
                              void* d_out, int out_size, void* d_ws, size_t ws_size,
                              hipStream_t stream) {
  const float* res   = (const float*)d_in[0];
  const float* wfc   = (const float*)d_in[1];
  const float* wproj = (const float*)d_in[2];
  const float* g     = (const float*)d_in[3];
  const float* b     = (const float*)d_in[4];
  float* out = (float*)d_out;

  unsigned short* xq = (unsigned short*)d_ws;              // 32768*256 bf16 = 16 MB
  unsigned short* kq = xq + (size_t)MROWS * D_;            // 4096*256 bf16  =  2 MB
  unsigned short* vq = kq + (size_t)S_TOT * D_;            // 4096*256 bf16  =  2 MB

  ln_kernel<<<2048, 256, 0, stream>>>(res, g, b, xq);
  prep_k<<<512, 256, 0, stream>>>(wfc, kq);
  prep_v<<<128, 256, 0, stream>>>(wproj, vq);
  mlpmha_main<<<256, 512, 0, stream>>>(xq, kq, vq, res, out);
}

// Round 7
// 265.745 us; speedup vs baseline: 4.1344x; 4.1344x over previous
//
#include <hip/hip_runtime.h>
#include <hip/hip_bf16.h>

typedef __attribute__((ext_vector_type(8))) short bf16x8;
typedef __attribute__((ext_vector_type(4))) float f32x4;

#define C_    1024
#define MROWS 32768   // B*T*QH
#define D_    256     // per-head dim
#define S_TOT 4096
#define SCH   32      // S-chunk
#define NCH   (S_TOT / SCH)   // 128 chunks

__device__ __forceinline__ unsigned short f2bf(float f) {
  union { float f; unsigned int u; } v; v.f = f;
  unsigned int u = v.u;
  u += 0x7fffu + ((u >> 16) & 1u);   // round-to-nearest-even
  return (unsigned short)(u >> 16);
}

__device__ __forceinline__ void async16(const void* g, void* l) {
  __builtin_amdgcn_global_load_lds(
      (const __attribute__((address_space(1))) unsigned int*)g,
      (__attribute__((address_space(3))) unsigned int*)l, 16, 0, 0);
}

// ---------------- merged prep: K and V -> bf16 fragment-linear --------------
// blocks 0..511: K.  kq[((sc2*8+kc)*2+sn)*64+lane][j] = K[s][d],
//   s = sc2*32 + sn*16 + (lane&15), d = kc*32 + (lane>>4)*8 + j
// blocks 512..639: V. vq[((sc2*16+dn)*64+lane)*8+j] = V[s][d],
//   s = sc2*32 + (lane>>4)*8 + j, d = dn*16 + (lane&15)
//   V[s][d] = w_proj[(s&3)*256 + d][s>>2]
__global__ __launch_bounds__(256) void prep_kv(const float* __restrict__ wfc,
                                               const float* __restrict__ wproj,
                                               unsigned short* __restrict__ kq,
                                               unsigned short* __restrict__ vq) {
  __shared__ unsigned short tile[8192];
  if (blockIdx.x < 512) {
    int t = blockIdx.x * 256 + threadIdx.x;
    int lane = t & 63;
    int sn  = (t >> 6) & 1;
    int kc  = (t >> 7) & 7;
    int sc2 = t >> 10;
    int s = sc2 * 32 + sn * 16 + (lane & 15);
    int d = kc * 32 + (lane >> 4) * 8;
    const float* src = wfc + (size_t)s * D_ + d;
    float4 a = *(const float4*)src;
    float4 b = *(const float4*)(src + 4);
    unsigned short o[8] = { f2bf(a.x), f2bf(a.y), f2bf(a.z), f2bf(a.w),
                            f2bf(b.x), f2bf(b.y), f2bf(b.z), f2bf(b.w) };
    *(uint4*)(kq + (size_t)t * 8) = *(uint4*)o;
  } else {
    int b = blockIdx.x - 512;
    int tid = threadIdx.x;
    int c0 = b * 8;
    #pragma unroll
    for (int it = 0; it < 4; ++it) {
      int row = it * 256 + tid;
      const float* src = wproj + (size_t)row * C_ + c0;
      float4 a = *(const float4*)src;
      float4 bb = *(const float4*)(src + 4);
      unsigned short* dst = &tile[row * 8];
      dst[0] = f2bf(a.x);  dst[1] = f2bf(a.y);  dst[2] = f2bf(a.z);  dst[3] = f2bf(a.w);
      dst[4] = f2bf(bb.x); dst[5] = f2bf(bb.y); dst[6] = f2bf(bb.z); dst[7] = f2bf(bb.w);
    }
    __syncthreads();
    #pragma unroll
    for (int it = 0; it < 4; ++it) {
      int slot = it * 256 + tid;
      int lane = slot & 63;
      int dn   = slot >> 6;
      int d = dn * 16 + (lane & 15);
      int sl0 = (lane >> 4) * 8;
      unsigned short o[8];
      #pragma unroll
      for (int j = 0; j < 8; ++j) {
        int sl = sl0 + j;
        o[j] = tile[((sl & 3) * 256 + d) * 8 + (sl >> 2)];
      }
      *(uint4*)(vq + (size_t)b * 8192 + (size_t)slot * 8) = *(uint4*)o;
    }
  }
}

// ---------------- fused main: LN prologue + R0 loop (byte-identical) --------
// Block owns Q rows wgM..wgM+127  <=>  residual rows blockIdx*32..+31.
// Prologue: issue K0 DMA, LayerNorm 32 residual rows -> qtile (LDS, bf16),
// then load Q fragments from qtile.  Main loop / layouts / epilogue = R0.
__global__ __launch_bounds__(512, 2) void mlpmha_main(
    const unsigned short* __restrict__ kq,
    const unsigned short* __restrict__ vq,
    const float* __restrict__ res,
    const float* __restrict__ g,
    const float* __restrict__ b,
    float* __restrict__ out) {
  __shared__ unsigned short ldsK[2][8192];   // 16KB x2, fragment-linear
  __shared__ unsigned short ldsV[8192];      // 16KB, fragment-linear
  __shared__ unsigned short ldsP[128][36];   // +4 pad
  __shared__ unsigned short qtile[32 * 1024];  // 64KB: LN'd residual rows (bf16)

  int tid  = threadIdx.x;
  int wave = tid >> 6;
  int lane = tid & 63;
  int l16  = lane & 15;
  int quad = lane >> 4;
  int wgM  = blockIdx.x * 128;

  // scores assignment: wave = (mi, si) -> 32 rows, 16 s-cols
  int mi = wave & 3, si = wave >> 2;
  // PV assignment: wave = (ni, mi2) -> 64 cols, 64 rows
  int ni = wave & 3, mi2 = wave >> 2;

  int soff = tid * 8;   // staging offset (shorts): wave-uniform base + lane*16B

  // prologue: K chunk 0 -> buf 0 (DMA flies under the LN compute)
  {
    const unsigned short* kg = kq + soff;
    async16(kg, &ldsK[0][soff]);
    async16(kg + 4096, &ldsK[0][soff + 4096]);
  }

  // ---- LayerNorm: 8 waves x 4 rows -> qtile (identical arithmetic to R0's ln_kernel)
  {
    int rb = blockIdx.x * 32;
    #pragma unroll
    for (int it = 0; it < 4; ++it) {
      int lrow = wave * 4 + it;
      const float* r = res + (size_t)(rb + lrow) * C_;
      float4 x[4];
      float s = 0.f, s2 = 0.f;
      #pragma unroll
      for (int i = 0; i < 4; ++i) {
        x[i] = *(const float4*)(r + i * 256 + lane * 4);
        s  += x[i].x + x[i].y + x[i].z + x[i].w;
        s2 += x[i].x * x[i].x + x[i].y * x[i].y + x[i].z * x[i].z + x[i].w * x[i].w;
      }
      #pragma unroll
      for (int off = 32; off > 0; off >>= 1) {
        s  += __shfl_xor(s, off, 64);
        s2 += __shfl_xor(s2, off, 64);
      }
      float mu  = s * (1.0f / C_);
      float var = s2 * (1.0f / C_) - mu * mu;
      float rs  = rsqrtf(var + 1e-5f);
      #pragma unroll
      for (int i = 0; i < 4; ++i) {
        int c = i * 256 + lane * 4;
        float4 gg = *(const float4*)(g + c);
        float4 bb = *(const float4*)(b + c);
        unsigned short o[4];
        o[0] = f2bf((x[i].x - mu) * rs * gg.x + bb.x);
        o[1] = f2bf((x[i].y - mu) * rs * gg.y + bb.y);
        o[2] = f2bf((x[i].z - mu) * rs * gg.z + bb.z);
        o[3] = f2bf((x[i].w - mu) * rs * gg.w + bb.w);
        *(ushort4*)(&qtile[lrow * 1024 + c]) = *(ushort4*)o;
      }
    }
  }
  __syncthreads();   // qtile visible; K0 drained

  // ---- Q fragments from qtile: Q row q=wgM+ql -> residual row ql>>2, col (ql&3)*256+...
  bf16x8 qf[2][8];
  #pragma unroll
  for (int mt = 0; mt < 2; ++mt) {
    int ql = mi * 32 + mt * 16 + l16;
    const unsigned short* qr = &qtile[(ql >> 2) * 1024 + (ql & 3) * 256 + quad * 8];
    #pragma unroll
    for (int kc = 0; kc < 8; ++kc) qf[mt][kc] = *(const bf16x8*)(qr + kc * 32);
  }

  f32x4 acc[4][4];   // [mt2][dnl]
  #pragma unroll
  for (int i = 0; i < 4; ++i)
    #pragma unroll
    for (int j = 0; j < 4; ++j) acc[i][j] = (f32x4){0.f, 0.f, 0.f, 0.f};

  for (int sc = 0; sc < NCH; ++sc) {
    int cur = sc & 1;

    // prefetch V(sc) during scores
    {
      const unsigned short* vg = vq + (size_t)sc * 8192 + soff;
      async16(vg, &ldsV[soff]);
      async16(vg + 4096, &ldsV[soff + 4096]);
    }

    // ---- scores: 32 rows x 16 s-cols per wave, K=256
    f32x4 sacc[2];
    sacc[0] = (f32x4){0.f, 0.f, 0.f, 0.f};
    sacc[1] = (f32x4){0.f, 0.f, 0.f, 0.f};
    #pragma unroll
    for (int kc = 0; kc < 8; ++kc) {
      bf16x8 kb = *(const bf16x8*)&ldsK[cur][(kc * 2 + si) * 512 + lane * 8];
      #pragma unroll
      for (int mt = 0; mt < 2; ++mt)
        sacc[mt] = __builtin_amdgcn_mfma_f32_16x16x32_bf16(qf[mt][kc], kb, sacc[mt], 0, 0, 0);
    }

    // ---- P = relu(score)^2 -> shared LDS
    #pragma unroll
    for (int mt = 0; mt < 2; ++mt)
      #pragma unroll
      for (int r = 0; r < 4; ++r) {
        float v = sacc[mt][r];
        v = v > 0.f ? v * v : 0.f;
        ldsP[mi * 32 + mt * 16 + quad * 4 + r][si * 16 + l16] = f2bf(v);
      }

    __syncthreads();   // P visible; V(sc) drained

    // prefetch K(sc+1) during PV
    if (sc + 1 < NCH) {
      const unsigned short* kg = kq + (size_t)(sc + 1) * 8192 + soff;
      async16(kg, &ldsK[1 - cur][soff]);
      async16(kg + 4096, &ldsK[1 - cur][soff + 4096]);
    }

    // ---- PV: 64 rows x 64 cols per wave, K = 32
    {
      bf16x8 vb[4];
      #pragma unroll
      for (int dnl = 0; dnl < 4; ++dnl)
        vb[dnl] = *(const bf16x8*)&ldsV[((ni * 4 + dnl) * 64 + lane) * 8];
      #pragma unroll
      for (int mt2 = 0; mt2 < 4; ++mt2) {
        const unsigned short* pp = &ldsP[mi2 * 64 + mt2 * 16 + l16][quad * 8];
        union { ushort4 h[2]; bf16x8 v; } pu;
        pu.h[0] = *(const ushort4*)pp;
        pu.h[1] = *(const ushort4*)(pp + 4);
        bf16x8 pa = pu.v;
        #pragma unroll
        for (int dnl = 0; dnl < 4; ++dnl)
          acc[mt2][dnl] = __builtin_amdgcn_mfma_f32_16x16x32_bf16(pa, vb[dnl], acc[mt2][dnl], 0, 0, 0);
      }
    }

    __syncthreads();   // P/V reusable; K(sc+1) drained
  }

  // ---- epilogue: out = residual + acc
  #pragma unroll
  for (int mt2 = 0; mt2 < 4; ++mt2)
    #pragma unroll
    for (int r = 0; r < 4; ++r) {
      size_t row = (size_t)(wgM + mi2 * 64 + mt2 * 16 + quad * 4 + r) * D_;
      #pragma unroll
      for (int dnl = 0; dnl < 4; ++dnl) {
        size_t idx = row + ni * 64 + dnl * 16 + l16;
        out[idx] = res[idx] + acc[mt2][dnl][r];
      }
    }
}

extern "C" void kernel_launch(void* const* d_in, const int* in_sizes, int n_in,
                              void* d_out, int out_size, void* d_ws, size_t ws_size,
                              hipStream_t stream) {
  const float* res   = (const float*)d_in[0];
  const float* wfc   = (const float*)d_in[1];
  const float* wproj = (const float*)d_in[2];
  const float* g     = (const float*)d_in[3];
  const float* b     = (const float*)d_in[4];
  float* out = (float*)d_out;

  unsigned short* kq = (unsigned short*)d_ws;              // 4096*256 bf16 = 2 MB
  unsigned short* vq = kq + (size_t)S_TOT * D_;            // 4096*256 bf16 = 2 MB

  prep_kv<<<640, 256, 0, stream>>>(wfc, wproj, kq, vq);
  mlpmha_main<<<256, 512, 0, stream>>>(kq, vq, res, g, b, out);
}

// Round 8
// 258.357 us; speedup vs baseline: 4.2526x; 1.0286x over previous
//
#include <hip/hip_runtime.h>
#include <hip/hip_bf16.h>

typedef __attribute__((ext_vector_type(8))) short bf16x8;
typedef __attribute__((ext_vector_type(4))) float f32x4;

#define C_    1024
#define MROWS 32768   // B*T*QH
#define D_    256     // per-head dim
#define S_TOT 4096
#define SCH   32      // S-chunk
#define NCH   (S_TOT / SCH)   // 128 chunks

__device__ __forceinline__ unsigned short f2bf(float f) {
  union { float f; unsigned int u; } v; v.f = f;
  unsigned int u = v.u;
  u += 0x7fffu + ((u >> 16) & 1u);   // round-to-nearest-even
  return (unsigned short)(u >> 16);
}

__device__ __forceinline__ void async16(const void* g, void* l) {
  __builtin_amdgcn_global_load_lds(
      (const __attribute__((address_space(1))) unsigned int*)g,
      (__attribute__((address_space(3))) unsigned int*)l, 16, 0, 0);
}

// ---------------- LayerNorm -> bf16 (one wave per row) ----------------
__global__ __launch_bounds__(256) void ln_kernel(const float* __restrict__ res,
                                                 const float* __restrict__ g,
                                                 const float* __restrict__ b,
                                                 unsigned short* __restrict__ xq) {
  int wave = threadIdx.x >> 6, lane = threadIdx.x & 63;
  int row = blockIdx.x * 4 + wave;
  const float* r = res + (size_t)row * C_;
  float4 x[4];
  float s = 0.f, s2 = 0.f;
  #pragma unroll
  for (int i = 0; i < 4; ++i) {
    x[i] = *(const float4*)(r + i * 256 + lane * 4);
    s  += x[i].x + x[i].y + x[i].z + x[i].w;
    s2 += x[i].x * x[i].x + x[i].y * x[i].y + x[i].z * x[i].z + x[i].w * x[i].w;
  }
  #pragma unroll
  for (int off = 32; off > 0; off >>= 1) {
    s  += __shfl_xor(s, off, 64);
    s2 += __shfl_xor(s2, off, 64);
  }
  float mu  = s * (1.0f / C_);
  float var = s2 * (1.0f / C_) - mu * mu;
  float rs  = rsqrtf(var + 1e-5f);
  #pragma unroll
  for (int i = 0; i < 4; ++i) {
    int c = i * 256 + lane * 4;
    float4 gg = *(const float4*)(g + c);
    float4 bb = *(const float4*)(b + c);
    unsigned short o[4];
    o[0] = f2bf((x[i].x - mu) * rs * gg.x + bb.x);
    o[1] = f2bf((x[i].y - mu) * rs * gg.y + bb.y);
    o[2] = f2bf((x[i].z - mu) * rs * gg.z + bb.z);
    o[3] = f2bf((x[i].w - mu) * rs * gg.w + bb.w);
    *(ushort4*)(xq + (size_t)row * C_ + c) = *(ushort4*)o;
  }
}

// ---------------- K -> bf16, pre-swizzled into MFMA B-fragment order --------
// kq[((sc2*8+kc)*2+sn)*64+lane][j] = K[s][d],
//   s = sc2*32 + sn*16 + (lane&15), d = kc*32 + (lane>>4)*8 + j
__global__ __launch_bounds__(256) void prep_k(const float* __restrict__ wfc,
                                              unsigned short* __restrict__ kq) {
  int t = blockIdx.x * 256 + threadIdx.x;
  int lane = t & 63;
  int sn  = (t >> 6) & 1;
  int kc  = (t >> 7) & 7;
  int sc2 = t >> 10;
  int s = sc2 * 32 + sn * 16 + (lane & 15);
  int d = kc * 32 + (lane >> 4) * 8;
  const float* src = wfc + (size_t)s * D_ + d;
  float4 a = *(const float4*)src;
  float4 b = *(const float4*)(src + 4);
  unsigned short o[8] = { f2bf(a.x), f2bf(a.y), f2bf(a.z), f2bf(a.w),
                          f2bf(b.x), f2bf(b.y), f2bf(b.z), f2bf(b.w) };
  *(uint4*)(kq + (size_t)t * 8) = *(uint4*)o;
}

// ---------------- V -> bf16, pre-swizzled into MFMA B-fragment order --------
// vq[((sc2*16+dn)*64+lane)*8+j] = V[s][d],
//   s = sc2*32 + (lane>>4)*8 + j, d = dn*16 + (lane&15)
//   V[s][d] = w_proj[(s&3)*256 + d][s>>2]
__global__ __launch_bounds__(256) void prep_v(const float* __restrict__ wproj,
                                              unsigned short* __restrict__ vq) {
  __shared__ unsigned short tile[8192];   // [p=(s&3)*256+d][c=(s_local>>2)] : 1024 x 8
  int b = blockIdx.x;
  int tid = threadIdx.x;
  int c0 = b * 8;
  #pragma unroll
  for (int it = 0; it < 4; ++it) {
    int row = it * 256 + tid;
    const float* src = wproj + (size_t)row * C_ + c0;
    float4 a = *(const float4*)src;
    float4 bb = *(const float4*)(src + 4);
    unsigned short* dst = &tile[row * 8];
    dst[0] = f2bf(a.x);  dst[1] = f2bf(a.y);  dst[2] = f2bf(a.z);  dst[3] = f2bf(a.w);
    dst[4] = f2bf(bb.x); dst[5] = f2bf(bb.y); dst[6] = f2bf(bb.z); dst[7] = f2bf(bb.w);
  }
  __syncthreads();
  #pragma unroll
  for (int it = 0; it < 4; ++it) {
    int slot = it * 256 + tid;
    int lane = slot & 63;
    int dn   = slot >> 6;
    int d = dn * 16 + (lane & 15);
    int sl0 = (lane >> 4) * 8;
    unsigned short o[8];
    #pragma unroll
    for (int j = 0; j < 8; ++j) {
      int sl = sl0 + j;
      o[j] = tile[((sl & 3) * 256 + d) * 8 + (sl >> 2)];
    }
    *(uint4*)(vq + (size_t)b * 8192 + (size_t)slot * 8) = *(uint4*)o;
  }
}

// ---------------- fused main: R0 layouts + 4-phase counted-vmcnt schedule ---
// Phases per 32-s chunk (T3+T4+T5 port; layouts/fragments identical to R0):
//  P1: kb[0..3]->regs, issue V(sc) DMA | bar | lgkm0 | prio1 8xMFMA prio0 | bar
//  P2: kb[4..7]->regs, issue K(next) DMA (dummy on last) | bar | lgkm0 | 8xMFMA | bar
//  P3: P=relu(s)^2 -> ldsP | vmcnt(2) lgkm0 | bar   (collective: V landed, P visible; K flying)
//  P4: pa/vb->regs | lgkm0 | prio1 16xMFMA prio0 | vmcnt(0) | bar (collective: K landed)
// Every cross-wave hazard = waitcnt THEN barrier (per-wave vmcnt alone is not
// collective).  sched_barrier(0) after each inline waitcnt (rule 18).
__global__ __launch_bounds__(512, 2) void mlpmha_main(
    const unsigned short* __restrict__ xq,
    const unsigned short* __restrict__ kq,
    const unsigned short* __restrict__ vq,
    const float* __restrict__ res,
    float* __restrict__ out) {
  __shared__ unsigned short ldsK[2][8192];   // 16KB x2, fragment-linear
  __shared__ unsigned short ldsV[8192];      // 16KB, fragment-linear
  __shared__ unsigned short ldsP[128][36];   // +4 pad

  int tid  = threadIdx.x;
  int wave = tid >> 6;
  int lane = tid & 63;
  int l16  = lane & 15;
  int quad = lane >> 4;
  int wgM  = blockIdx.x * 128;

  // scores assignment: wave = (mi, si) -> 32 rows, 16 s-cols
  int mi = wave & 3, si = wave >> 2;
  // PV assignment: wave = (ni, mi2) -> 64 cols, 64 rows
  int ni = wave & 3, mi2 = wave >> 2;

  // Q fragments: 2 m-tiles x 8 k-chunks, register resident
  bf16x8 qf[2][8];
  #pragma unroll
  for (int mt = 0; mt < 2; ++mt) {
    const unsigned short* qr =
        xq + (size_t)(wgM + mi * 32 + mt * 16 + l16) * D_ + quad * 8;
    #pragma unroll
    for (int kc = 0; kc < 8; ++kc) qf[mt][kc] = *(const bf16x8*)(qr + kc * 32);
  }

  f32x4 acc[4][4];   // [mt2][dnl]
  #pragma unroll
  for (int i = 0; i < 4; ++i)
    #pragma unroll
    for (int j = 0; j < 4; ++j) acc[i][j] = (f32x4){0.f, 0.f, 0.f, 0.f};

  int soff = tid * 8;   // staging offset (shorts): wave-uniform base + lane*16B

  // prologue: K chunk 0 -> buf 0 ; collective landed
  {
    const unsigned short* kg = kq + soff;
    async16(kg, &ldsK[0][soff]);
    async16(kg + 4096, &ldsK[0][soff + 4096]);
  }
  asm volatile("s_waitcnt vmcnt(0)" ::: "memory");
  __builtin_amdgcn_s_barrier();

  for (int sc = 0; sc < NCH; ++sc) {
    int cur = sc & 1;
    f32x4 sacc[2];
    sacc[0] = (f32x4){0.f, 0.f, 0.f, 0.f};
    sacc[1] = (f32x4){0.f, 0.f, 0.f, 0.f};

    // ---- P1: kb 0..3 -> regs, V(sc) DMA, scores kc=0..3
    bf16x8 kbr[4];
    #pragma unroll
    for (int kc = 0; kc < 4; ++kc)
      kbr[kc] = *(const bf16x8*)&ldsK[cur][(kc * 2 + si) * 512 + lane * 8];
    {
      const unsigned short* vg = vq + (size_t)sc * 8192 + soff;
      async16(vg, &ldsV[soff]);
      async16(vg + 4096, &ldsV[soff + 4096]);
    }
    __builtin_amdgcn_s_barrier();
    asm volatile("s_waitcnt lgkmcnt(0)" ::: "memory");
    __builtin_amdgcn_sched_barrier(0);
    __builtin_amdgcn_s_setprio(1);
    #pragma unroll
    for (int kc = 0; kc < 4; ++kc)
      #pragma unroll
      for (int mt = 0; mt < 2; ++mt)
        sacc[mt] = __builtin_amdgcn_mfma_f32_16x16x32_bf16(qf[mt][kc], kbr[kc], sacc[mt], 0, 0, 0);
    __builtin_amdgcn_s_setprio(0);
    __builtin_amdgcn_s_barrier();

    // ---- P2: kb 4..7 -> regs, K(next) DMA (dummy K0 on last iter), scores kc=4..7
    #pragma unroll
    for (int kc = 0; kc < 4; ++kc)
      kbr[kc] = *(const bf16x8*)&ldsK[cur][((kc + 4) * 2 + si) * 512 + lane * 8];
    {
      int nsc = (sc + 1 < NCH) ? sc + 1 : 0;   // dummy keeps vmcnt shape uniform
      const unsigned short* kg = kq + (size_t)nsc * 8192 + soff;
      async16(kg, &ldsK[1 - cur][soff]);
      async16(kg + 4096, &ldsK[1 - cur][soff + 4096]);
    }
    __builtin_amdgcn_s_barrier();
    asm volatile("s_waitcnt lgkmcnt(0)" ::: "memory");
    __builtin_amdgcn_sched_barrier(0);
    __builtin_amdgcn_s_setprio(1);
    #pragma unroll
    for (int kc = 0; kc < 4; ++kc)
      #pragma unroll
      for (int mt = 0; mt < 2; ++mt)
        sacc[mt] = __builtin_amdgcn_mfma_f32_16x16x32_bf16(qf[mt][kc + 4], kbr[kc], sacc[mt], 0, 0, 0);
    __builtin_amdgcn_s_setprio(0);
    __builtin_amdgcn_s_barrier();

    // ---- P3: P = relu(score)^2 -> ldsP ; collective V-landed + P-visible
    #pragma unroll
    for (int mt = 0; mt < 2; ++mt)
      #pragma unroll
      for (int r = 0; r < 4; ++r) {
        float v = sacc[mt][r];
        v = v > 0.f ? v * v : 0.f;
        ldsP[mi * 32 + mt * 16 + quad * 4 + r][si * 16 + l16] = f2bf(v);
      }
    asm volatile("s_waitcnt vmcnt(2) lgkmcnt(0)" ::: "memory");
    __builtin_amdgcn_s_barrier();

    // ---- P4: pa/vb -> regs, PV MFMAs ; collective K-landed at exit
    {
      bf16x8 vb[4];
      #pragma unroll
      for (int dnl = 0; dnl < 4; ++dnl)
        vb[dnl] = *(const bf16x8*)&ldsV[((ni * 4 + dnl) * 64 + lane) * 8];
      bf16x8 pa[4];
      #pragma unroll
      for (int mt2 = 0; mt2 < 4; ++mt2) {
        const unsigned short* pp = &ldsP[mi2 * 64 + mt2 * 16 + l16][quad * 8];
        union { ushort4 h[2]; bf16x8 v; } pu;
        pu.h[0] = *(const ushort4*)pp;
        pu.h[1] = *(const ushort4*)(pp + 4);
        pa[mt2] = pu.v;
      }
      asm volatile("s_waitcnt lgkmcnt(0)" ::: "memory");
      __builtin_amdgcn_sched_barrier(0);
      __builtin_amdgcn_s_setprio(1);
      #pragma unroll
      for (int mt2 = 0; mt2 < 4; ++mt2)
        #pragma unroll
        for (int dnl = 0; dnl < 4; ++dnl)
          acc[mt2][dnl] = __builtin_amdgcn_mfma_f32_16x16x32_bf16(pa[mt2], vb[dnl], acc[mt2][dnl], 0, 0, 0);
      __builtin_amdgcn_s_setprio(0);
    }
    asm volatile("s_waitcnt vmcnt(0)" ::: "memory");
    __builtin_amdgcn_s_barrier();
  }

  // ---- epilogue: out = residual + acc
  #pragma unroll
  for (int mt2 = 0; mt2 < 4; ++mt2)
    #pragma unroll
    for (int r = 0; r < 4; ++r) {
      size_t row = (size_t)(wgM + mi2 * 64 + mt2 * 16 + quad * 4 + r) * D_;
      #pragma unroll
      for (int dnl = 0; dnl < 4; ++dnl) {
        size_t idx = row + ni * 64 + dnl * 16 + l16;
        out[idx] = res[idx] + acc[mt2][dnl][r];
      }
    }
}

extern "C" void kernel_launch(void* const* d_in, const int* in_sizes, int n_in,
                              void* d_out, int out_size, void* d_ws, size_t ws_size,
                              hipStream_t stream) {
  const float* res   = (const float*)d_in[0];
  const float* wfc   = (const float*)d_in[1];
  const float* wproj = (const float*)d_in[2];
  const float* g     = (const float*)d_in[3];
  const float* b     = (const float*)d_in[4];
  float* out = (float*)d_out;

  unsigned short* xq = (unsigned short*)d_ws;              // 32768*256 bf16 = 16 MB
  unsigned short* kq = xq + (size_t)MROWS * D_;            // 4096*256 bf16  =  2 MB
  unsigned short* vq = kq + (size_t)S_TOT * D_;            // 4096*256 bf16  =  2 MB

  ln_kernel<<<2048, 256, 0, stream>>>(res, g, b, xq);
  prep_k<<<512, 256, 0, stream>>>(wfc, kq);
  prep_v<<<128, 256, 0, stream>>>(wproj, vq);
  mlpmha_main<<<256, 512, 0, stream>>>(xq, kq, vq, res, out);
}